// Round 1
// baseline (200.093 us; speedup 1.0000x reference)
//
#include <hip/hip_runtime.h>

#define SEQ 8192
#define DIM 2048
#define NEG 0.02f

// ---------------------------------------------------------------------------
// K1: conv1  [2048 -> 16, k=3, pad=1] + leaky
// grid 256, block 256. T=32 output positions per block.
// thread: c = tid&15 (out channel), tg = tid>>4 (0..15) -> outputs t = t0+2*tg+{0,1}
// LDS: xs transposed [cin 128][44 floats (rows 0..33 = t0-1..t0+32)]
//      wsw [16 c][99 float4] = w1 chunk (cin-major, k-minor: 12 floats / 4 cin)
// Register-prefetch of next chunk hides global latency under compute.
// ---------------------------------------------------------------------------
__device__ __forceinline__ void conv1_load_chunk(
    const float* __restrict__ x, const float4* __restrict__ w1_4,
    int t0, int ci, int rg, int chunk, const int* wc, const int* wj,
    float xr[20], float4 wr[6]) {
  const int cc = chunk * 128;
  #pragma unroll
  for (int p = 0; p < 5; ++p) {
    #pragma unroll
    for (int e = 0; e < 4; ++e) {
      int r = 8 * p + 4 * rg + e;        // row 0..35 (34 used)
      int gt = t0 - 1 + r;               // global t
      bool ok = (r < 34) && (gt >= 0) && (gt < SEQ);
      xr[p * 4 + e] = ok ? x[gt * DIM + cc + ci] : 0.f;
    }
  }
  #pragma unroll
  for (int j = 0; j < 6; ++j)
    wr[j] = w1_4[wc[j] * 1536 + chunk * 96 + wj[j]];
}

__global__ __launch_bounds__(256) void k_conv1(
    const float* __restrict__ x, const float* __restrict__ w1,
    const float* __restrict__ b1, float* __restrict__ out1) {
  __shared__ float4 wsw[16 * 99];      // 25.3 KB, stride 99 f4/channel (2-way bank max)
  __shared__ float2 xsh[128 * 22];     // 22.5 KB, stride 22 f2 = 44 f per cin
  float* xsf = (float*)xsh;

  const int tid = threadIdx.x;
  const int c  = tid & 15;
  const int tg = tid >> 4;
  const int t0 = blockIdx.x * 32;
  const int ci = tid & 127;            // staging col
  const int rg = tid >> 7;             // staging row group
  const float4* w1_4 = (const float4*)w1;

  int wc[6], wj[6];
  #pragma unroll
  for (int j = 0; j < 6; ++j) {
    int f4 = j * 256 + tid;
    wc[j] = f4 / 96;
    wj[j] = f4 - wc[j] * 96;
  }

  float xr[20];
  float4 wr[6];
  conv1_load_chunk(x, w1_4, t0, ci, rg, 0, wc, wj, xr, wr);

  float aA0 = 0.f, aA1 = 0.f, aB0 = 0.f, aB1 = 0.f;

  for (int ch = 0; ch < 16; ++ch) {
    __syncthreads();
    // write staged regs -> LDS
    #pragma unroll
    for (int p = 0; p < 5; ++p) {
      #pragma unroll
      for (int e = 0; e < 4; ++e) {
        int r = 8 * p + 4 * rg + e;
        if (r < 34) xsf[ci * 44 + r] = xr[p * 4 + e];
      }
    }
    #pragma unroll
    for (int j = 0; j < 6; ++j) wsw[wc[j] * 99 + wj[j]] = wr[j];
    __syncthreads();

    if (ch < 15)
      conv1_load_chunk(x, w1_4, t0, ci, rg, ch + 1, wc, wj, xr, wr);

    // compute: 128 cin = 32 groups of 4
    #pragma unroll 4
    for (int g = 0; g < 32; ++g) {
      const int wb = c * 99 + g * 3;
      float4 wa = wsw[wb + 0];
      float4 wb4 = wsw[wb + 1];
      float4 wc4 = wsw[wb + 2];
      const int xb = 88 * g + tg;      // (4g)*22 + tg
      float2 p0 = xsh[xb +  0], q0 = xsh[xb +  1];
      float2 p1 = xsh[xb + 22], q1 = xsh[xb + 23];
      float2 p2 = xsh[xb + 44], q2 = xsh[xb + 45];
      float2 p3 = xsh[xb + 66], q3 = xsh[xb + 67];
      // e=0: k0..2 = wa.x wa.y wa.z
      aA0 += wa.x * p0.x + wa.y * p0.y + wa.z * q0.x;
      aA1 += wa.x * p0.y + wa.y * q0.x + wa.z * q0.y;
      // e=1: wa.w wb4.x wb4.y
      aB0 += wa.w * p1.x + wb4.x * p1.y + wb4.y * q1.x;
      aB1 += wa.w * p1.y + wb4.x * q1.x + wb4.y * q1.y;
      // e=2: wb4.z wb4.w wc4.x
      aA0 += wb4.z * p2.x + wb4.w * p2.y + wc4.x * q2.x;
      aA1 += wb4.z * p2.y + wb4.w * q2.x + wc4.x * q2.y;
      // e=3: wc4.y wc4.z wc4.w
      aB0 += wc4.y * p3.x + wc4.z * p3.y + wc4.w * q3.x;
      aB1 += wc4.y * p3.y + wc4.z * q3.x + wc4.w * q3.y;
    }
  }

  float bb = b1[c];
  float v0 = aA0 + aB0 + bb;
  float v1 = aA1 + aB1 + bb;
  v0 = (v0 >= 0.f) ? v0 : NEG * v0;
  v1 = (v1 >= 0.f) ? v1 : NEG * v1;
  const int t = t0 + 2 * tg;
  out1[c * SEQ + t + 0] = v0;
  out1[c * SEQ + t + 1] = v1;
}

// ---------------------------------------------------------------------------
// K2: conv2..conv5 fused (+leaky each). grid 128, block 128, T=64 per block.
// Local index j in 0..71 <-> global t = t0-4+j.
// ---------------------------------------------------------------------------
__global__ __launch_bounds__(128) void k_chain(
    const float* __restrict__ out1,
    const float* __restrict__ w2, const float* __restrict__ b2,
    const float* __restrict__ w3, const float* __restrict__ b3,
    const float* __restrict__ w4, const float* __restrict__ b4,
    const float* __restrict__ w5, const float* __restrict__ b5,
    float* __restrict__ y5) {
  __shared__ float l1[16][72], l2[8][72], l3[4][72], l4[2][72];
  __shared__ float w2s[384], w3s[96], w4s[24], w5s[6];
  __shared__ float bs[16];   // b2[0..7] b3[8..11] b4[12..13] b5[14]

  const int tid = threadIdx.x;
  const int t0 = blockIdx.x * 64;

  for (int i = tid; i < 384; i += 128) w2s[i] = w2[i];
  if (tid < 96) w3s[tid] = w3[tid];
  else if (tid < 120) w4s[tid - 96] = w4[tid - 96];
  else if (tid == 120) { for (int i = 0; i < 6; ++i) w5s[i] = w5[i]; }
  else if (tid == 121) {
    for (int i = 0; i < 8; ++i) bs[i] = b2[i];
    for (int i = 0; i < 4; ++i) bs[8 + i] = b3[i];
    bs[12] = b4[0]; bs[13] = b4[1]; bs[14] = b5[0];
  }
  for (int idx = tid; idx < 16 * 72; idx += 128) {
    int cc = idx / 72, j = idx - cc * 72;
    int gt = t0 - 4 + j;
    l1[cc][j] = (gt >= 0 && gt < SEQ) ? out1[cc * SEQ + gt] : 0.f;
  }
  __syncthreads();

  // conv2: j 1..70, c<8
  for (int o = tid; o < 560; o += 128) {
    int j = (o >> 3) + 1, cc = o & 7;
    float acc = bs[cc];
    #pragma unroll
    for (int ci = 0; ci < 16; ++ci) {
      acc += w2s[cc * 48 + ci * 3 + 0] * l1[ci][j - 1];
      acc += w2s[cc * 48 + ci * 3 + 1] * l1[ci][j];
      acc += w2s[cc * 48 + ci * 3 + 2] * l1[ci][j + 1];
    }
    l2[cc][j] = (acc >= 0.f) ? acc : NEG * acc;
  }
  __syncthreads();

  // conv3: j 2..69, c<4
  for (int o = tid; o < 272; o += 128) {
    int j = (o >> 2) + 2, cc = o & 3;
    float acc = bs[8 + cc];
    #pragma unroll
    for (int ci = 0; ci < 8; ++ci) {
      acc += w3s[cc * 24 + ci * 3 + 0] * l2[ci][j - 1];
      acc += w3s[cc * 24 + ci * 3 + 1] * l2[ci][j];
      acc += w3s[cc * 24 + ci * 3 + 2] * l2[ci][j + 1];
    }
    l3[cc][j] = (acc >= 0.f) ? acc : NEG * acc;
  }
  __syncthreads();

  // conv4: j 3..68, c<2
  for (int o = tid; o < 132; o += 128) {
    int j = (o >> 1) + 3, cc = o & 1;
    float acc = bs[12 + cc];
    #pragma unroll
    for (int ci = 0; ci < 4; ++ci) {
      acc += w4s[cc * 12 + ci * 3 + 0] * l3[ci][j - 1];
      acc += w4s[cc * 12 + ci * 3 + 1] * l3[ci][j];
      acc += w4s[cc * 12 + ci * 3 + 2] * l3[ci][j + 1];
    }
    l4[cc][j] = (acc >= 0.f) ? acc : NEG * acc;
  }
  __syncthreads();

  // conv5: j 4..67 -> y5[t0 + 0..63]
  for (int o = tid; o < 64; o += 128) {
    int j = o + 4;
    float acc = bs[14];
    #pragma unroll
    for (int ci = 0; ci < 2; ++ci) {
      acc += w5s[ci * 3 + 0] * l4[ci][j - 1];
      acc += w5s[ci * 3 + 1] * l4[ci][j];
      acc += w5s[ci * 3 + 2] * l4[ci][j + 1];
    }
    y5[t0 + o] = (acc >= 0.f) ? acc : NEG * acc;
  }
}

// ---------------------------------------------------------------------------
// K3: logits = Wl @ y5 + bl.  grid 2048 (4 rows/block), block 256.
// HBM-bound: streams 256 MiB of Wl with float4 lanes.
// ---------------------------------------------------------------------------
__global__ __launch_bounds__(256) void k_matvec(
    const float* __restrict__ Wl, const float* __restrict__ bl,
    const float* __restrict__ y5, float* __restrict__ logits) {
  const int tid = threadIdx.x;
  const int r0 = blockIdx.x * 4;
  const float4* W4 = (const float4*)Wl;
  const float4* y4 = (const float4*)y5;

  float a0 = 0.f, a1 = 0.f, a2 = 0.f, a3 = 0.f;
  #pragma unroll 2
  for (int u = 0; u < 8; ++u) {
    int i = u * 256 + tid;
    float4 yv = y4[i];
    float4 r0v = W4[(r0 + 0) * 2048 + i];
    float4 r1v = W4[(r0 + 1) * 2048 + i];
    float4 r2v = W4[(r0 + 2) * 2048 + i];
    float4 r3v = W4[(r0 + 3) * 2048 + i];
    a0 += r0v.x * yv.x + r0v.y * yv.y + r0v.z * yv.z + r0v.w * yv.w;
    a1 += r1v.x * yv.x + r1v.y * yv.y + r1v.z * yv.z + r1v.w * yv.w;
    a2 += r2v.x * yv.x + r2v.y * yv.y + r2v.z * yv.z + r2v.w * yv.w;
    a3 += r3v.x * yv.x + r3v.y * yv.y + r3v.z * yv.z + r3v.w * yv.w;
  }
  #pragma unroll
  for (int o = 32; o; o >>= 1) {
    a0 += __shfl_down(a0, o);
    a1 += __shfl_down(a1, o);
    a2 += __shfl_down(a2, o);
    a3 += __shfl_down(a3, o);
  }
  __shared__ float red[4][4];
  const int lane = tid & 63, wid = tid >> 6;
  if (lane == 0) { red[wid][0] = a0; red[wid][1] = a1; red[wid][2] = a2; red[wid][3] = a3; }
  __syncthreads();
  if (tid < 4) {
    float s = red[0][tid] + red[1][tid] + red[2][tid] + red[3][tid];
    logits[r0 + tid] = s + bl[r0 + tid];
  }
}

// ---------------------------------------------------------------------------
// K4: softmax stats (redundant per block, logits are L2-hot) + weighted sum
// partials. grid 256 = 128 t-chunks x 2 column strips, block 256.
// partial[tc][2048 floats]
// ---------------------------------------------------------------------------
__global__ __launch_bounds__(256) void k_wsum(
    const float* __restrict__ x, const float* __restrict__ logits,
    float* __restrict__ partial) {
  const int tid = threadIdx.x;
  const int strip = blockIdx.x & 1;
  const int tc = blockIdx.x >> 1;
  const int lane = tid & 63, wid = tid >> 6;
  __shared__ float red[4];
  __shared__ float MS[2];

  float m = -3.0e38f;
  for (int i = tid; i < SEQ; i += 256) m = fmaxf(m, logits[i]);
  #pragma unroll
  for (int o = 32; o; o >>= 1) m = fmaxf(m, __shfl_down(m, o));
  if (lane == 0) red[wid] = m;
  __syncthreads();
  if (tid == 0) MS[0] = fmaxf(fmaxf(red[0], red[1]), fmaxf(red[2], red[3]));
  __syncthreads();
  const float M = MS[0];

  float s = 0.f;
  for (int i = tid; i < SEQ; i += 256) s += expf(logits[i] - M);
  #pragma unroll
  for (int o = 32; o; o >>= 1) s += __shfl_down(s, o);
  __syncthreads();
  if (lane == 0) red[wid] = s;
  __syncthreads();
  if (tid == 0) MS[1] = red[0] + red[1] + red[2] + red[3];
  __syncthreads();
  const float invS = 1.0f / MS[1];

  const float4* x4 = (const float4*)x;
  float4 acc = make_float4(0.f, 0.f, 0.f, 0.f);
  const int t0 = tc * 64;
  const int col = strip * 256 + tid;   // float4 column 0..511
  for (int t = t0; t < t0 + 64; ++t) {
    float a = expf(logits[t] - M) * invS;
    float4 xv = x4[t * 512 + col];
    acc.x += a * xv.x; acc.y += a * xv.y; acc.z += a * xv.z; acc.w += a * xv.w;
  }
  float4* p4 = (float4*)partial;
  p4[tc * 512 + col] = acc;
}

// ---------------------------------------------------------------------------
// K5: out[d] = sum_{tc<128} partial[tc][d]. grid 2, block 256.
// ---------------------------------------------------------------------------
__global__ __launch_bounds__(256) void k_reduce(
    const float* __restrict__ partial, float* __restrict__ out) {
  const int d4 = blockIdx.x * 256 + threadIdx.x;  // 0..511
  const float4* p4 = (const float4*)partial;
  float4 acc = make_float4(0.f, 0.f, 0.f, 0.f);
  for (int c = 0; c < 128; ++c) {
    float4 v = p4[c * 512 + d4];
    acc.x += v.x; acc.y += v.y; acc.z += v.z; acc.w += v.w;
  }
  ((float4*)out)[d4] = acc;
}

// ---------------------------------------------------------------------------
extern "C" void kernel_launch(void* const* d_in, const int* in_sizes, int n_in,
                              void* d_out, int out_size, void* d_ws, size_t ws_size,
                              hipStream_t stream) {
  const float* x  = (const float*)d_in[0];
  const float* w1 = (const float*)d_in[1];
  const float* b1 = (const float*)d_in[2];
  const float* w2 = (const float*)d_in[3];
  const float* b2 = (const float*)d_in[4];
  const float* w3 = (const float*)d_in[5];
  const float* b3 = (const float*)d_in[6];
  const float* w4 = (const float*)d_in[7];
  const float* b4 = (const float*)d_in[8];
  const float* w5 = (const float*)d_in[9];
  const float* b5 = (const float*)d_in[10];
  const float* Wl = (const float*)d_in[11];
  const float* bl = (const float*)d_in[12];
  float* out = (float*)d_out;

  float* ws      = (float*)d_ws;
  float* out1    = ws;                  // 16*8192
  float* y5      = out1 + 16 * SEQ;     // 8192
  float* logits  = y5 + SEQ;            // 8192
  float* partial = logits + SEQ;        // 128*2048

  k_conv1 <<<256, 256, 0, stream>>>(x, w1, b1, out1);
  k_chain <<<128, 128, 0, stream>>>(out1, w2, b2, w3, b3, w4, b4, w5, b5, y5);
  k_matvec<<<2048, 256, 0, stream>>>(Wl, bl, y5, logits);
  k_wsum  <<<256, 256, 0, stream>>>(x, logits, partial);
  k_reduce<<<2, 256, 0, stream>>>(partial, out);
}

// Round 2
// 118.311 us; speedup vs baseline: 1.6913x; 1.6913x over previous
//
#include <hip/hip_runtime.h>

#define SEQ 8192
#define DIM 2048
#define NEG 0.02f

// ---------------------------------------------------------------------------
// K1: conv1 partials. grid 512 = 32 t-blocks x 16 cin-slices. block 256.
// Thread computes 4 channels x 4 t (16 acc). Block: all 16 c x 256 t,
// cin slice of 128 (4 LDS chunks of 32).
// LDS: wlds [32 gg][16 c][3 k][4 u] = 24KB (staged once per block)
//      xs   [32 cin][260 r]         = 33.3KB per chunk (transposed)
// Per 4-cin group per wave: 12 b128 (w) + 4x(b128+b64) (x) = ~216 LDS cyc
// vs 384 VALU cyc -> ~3x less LDS-per-FMA than previous version.
// ---------------------------------------------------------------------------
__global__ __launch_bounds__(256, 2) void k_conv1(
    const float* __restrict__ x, const float* __restrict__ w1,
    float* __restrict__ out1p) {
  __shared__ float wlds[32 * 16 * 12];
  __shared__ float xs[32 * 260];

  const int tid = threadIdx.x;
  const int tb = blockIdx.x & 31;
  const int slice = blockIdx.x >> 5;
  const int cinb = slice * 128;

  // stage w for the whole slice: w1[c][cinb+uu][k] -> wlds[gg][c][k][u]
  for (int i = tid; i < 6144; i += 256) {
    int c = i / 384;
    int rem = i - c * 384;
    int uu = rem / 3;
    int k = rem - uu * 3;
    float v = w1[c * 6144 + (cinb + uu) * 3 + k];
    wlds[((uu >> 2) * 16 + c) * 12 + k * 4 + (uu & 3)] = v;
  }

  const int cg = tid & 3;    // channels 4*cg + i
  const int tg = tid >> 2;   // 0..63 -> t = tb*256 + 4*tg + tt
  const int qc = tid & 7;    // staging: cin quad
  const int rs = tid >> 3;   // staging: row group

  float acc[4][4];
  #pragma unroll
  for (int i = 0; i < 4; ++i)
    #pragma unroll
    for (int tt = 0; tt < 4; ++tt) acc[i][tt] = 0.f;

  const float4* x4 = (const float4*)x;

  for (int ch = 0; ch < 4; ++ch) {
    __syncthreads();
    // stage x chunk: rows r=0..257 (gt = tb*256-1+r), 32 cin, transposed
    #pragma unroll
    for (int it = 0; it < 9; ++it) {
      int r = rs + it * 32;
      if (r < 258) {
        int gt = tb * 256 - 1 + r;
        float4 v = make_float4(0.f, 0.f, 0.f, 0.f);
        if (gt >= 0 && gt < SEQ)
          v = x4[gt * 512 + (cinb >> 2) + ch * 8 + qc];
        xs[(4 * qc + 0) * 260 + r] = v.x;
        xs[(4 * qc + 1) * 260 + r] = v.y;
        xs[(4 * qc + 2) * 260 + r] = v.z;
        xs[(4 * qc + 3) * 260 + r] = v.w;
      }
    }
    __syncthreads();

    #pragma unroll 1
    for (int gg = 0; gg < 8; ++gg) {
      const float4* wp = (const float4*)&wlds[(ch * 8 + gg) * 16 * 12];
      float4 wk[4][3];
      #pragma unroll
      for (int i = 0; i < 4; ++i)
        #pragma unroll
        for (int k = 0; k < 3; ++k)
          wk[i][k] = wp[(4 * cg + i) * 3 + k];
      const float* wkf = (const float*)wk;

      #pragma unroll
      for (int u = 0; u < 4; ++u) {
        const float* xb = &xs[(gg * 4 + u) * 260 + 4 * tg];
        float4 xa = *(const float4*)xb;
        float2 xt = *(const float2*)(xb + 4);
        float xv[6] = {xa.x, xa.y, xa.z, xa.w, xt.x, xt.y};
        #pragma unroll
        for (int i = 0; i < 4; ++i) {
          #pragma unroll
          for (int k = 0; k < 3; ++k) {
            float wv = wkf[(i * 3 + k) * 4 + u];
            #pragma unroll
            for (int tt = 0; tt < 4; ++tt)
              acc[i][tt] += wv * xv[tt + k];
          }
        }
      }
    }
  }

  // write partials (no bias/leaky here -- k_chain finishes)
  #pragma unroll
  for (int i = 0; i < 4; ++i) {
    float4 o = make_float4(acc[i][0], acc[i][1], acc[i][2], acc[i][3]);
    int c = 4 * cg + i;
    ((float4*)out1p)[(slice * 16 + c) * 2048 + tb * 64 + tg] = o;
  }
}

// ---------------------------------------------------------------------------
// K2: sum conv1 partials + bias + leaky, then conv2..conv5 fused.
// grid 128, block 128, T=64 per block. j in 0..71 <-> t = t0-4+j.
// ---------------------------------------------------------------------------
__global__ __launch_bounds__(128) void k_chain(
    const float* __restrict__ out1p, const float* __restrict__ b1,
    const float* __restrict__ w2, const float* __restrict__ b2,
    const float* __restrict__ w3, const float* __restrict__ b3,
    const float* __restrict__ w4, const float* __restrict__ b4,
    const float* __restrict__ w5, const float* __restrict__ b5,
    float* __restrict__ y5) {
  __shared__ float l1[16][72], l2[8][72], l3[4][72], l4[2][72];
  __shared__ float w2s[384], w3s[96], w4s[24], w5s[6];
  __shared__ float bs[16];

  const int tid = threadIdx.x;
  const int t0 = blockIdx.x * 64;

  for (int i = tid; i < 384; i += 128) w2s[i] = w2[i];
  if (tid < 96) w3s[tid] = w3[tid];
  else if (tid < 120) w4s[tid - 96] = w4[tid - 96];
  else if (tid == 120) { for (int i = 0; i < 6; ++i) w5s[i] = w5[i]; }
  else if (tid == 121) {
    for (int i = 0; i < 8; ++i) bs[i] = b2[i];
    for (int i = 0; i < 4; ++i) bs[8 + i] = b3[i];
    bs[12] = b4[0]; bs[13] = b4[1]; bs[14] = b5[0];
  }

  // l1[cc][j] = leaky(b1[cc] + sum_s out1p[s][cc][t0-4+j])
  const float4* p4 = (const float4*)out1p;
  for (int idx = tid; idx < 16 * 18; idx += 128) {
    int cc = idx / 18, m = idx - cc * 18;
    int gt0 = t0 - 4 + 4 * m;
    float4 a = make_float4(0.f, 0.f, 0.f, 0.f);
    if (gt0 >= 0 && gt0 < SEQ) {
      int base = cc * 2048 + (gt0 >> 2);
      #pragma unroll
      for (int s = 0; s < 16; ++s) {
        float4 v = p4[s * 16 * 2048 + base];
        a.x += v.x; a.y += v.y; a.z += v.z; a.w += v.w;
      }
    }
    float bb = b1[cc];
    float e0 = a.x + bb, e1 = a.y + bb, e2 = a.z + bb, e3 = a.w + bb;
    l1[cc][4 * m + 0] = (e0 >= 0.f) ? e0 : NEG * e0;
    l1[cc][4 * m + 1] = (e1 >= 0.f) ? e1 : NEG * e1;
    l1[cc][4 * m + 2] = (e2 >= 0.f) ? e2 : NEG * e2;
    l1[cc][4 * m + 3] = (e3 >= 0.f) ? e3 : NEG * e3;
  }
  __syncthreads();

  for (int o = tid; o < 560; o += 128) {
    int j = (o >> 3) + 1, cc = o & 7;
    float acc = bs[cc];
    #pragma unroll
    for (int ci = 0; ci < 16; ++ci) {
      acc += w2s[cc * 48 + ci * 3 + 0] * l1[ci][j - 1];
      acc += w2s[cc * 48 + ci * 3 + 1] * l1[ci][j];
      acc += w2s[cc * 48 + ci * 3 + 2] * l1[ci][j + 1];
    }
    l2[cc][j] = (acc >= 0.f) ? acc : NEG * acc;
  }
  __syncthreads();

  for (int o = tid; o < 272; o += 128) {
    int j = (o >> 2) + 2, cc = o & 3;
    float acc = bs[8 + cc];
    #pragma unroll
    for (int ci = 0; ci < 8; ++ci) {
      acc += w3s[cc * 24 + ci * 3 + 0] * l2[ci][j - 1];
      acc += w3s[cc * 24 + ci * 3 + 1] * l2[ci][j];
      acc += w3s[cc * 24 + ci * 3 + 2] * l2[ci][j + 1];
    }
    l3[cc][j] = (acc >= 0.f) ? acc : NEG * acc;
  }
  __syncthreads();

  for (int o = tid; o < 132; o += 128) {
    int j = (o >> 1) + 3, cc = o & 1;
    float acc = bs[12 + cc];
    #pragma unroll
    for (int ci = 0; ci < 4; ++ci) {
      acc += w4s[cc * 12 + ci * 3 + 0] * l3[ci][j - 1];
      acc += w4s[cc * 12 + ci * 3 + 1] * l3[ci][j];
      acc += w4s[cc * 12 + ci * 3 + 2] * l3[ci][j + 1];
    }
    l4[cc][j] = (acc >= 0.f) ? acc : NEG * acc;
  }
  __syncthreads();

  for (int o = tid; o < 64; o += 128) {
    int j = o + 4;
    float acc = bs[14];
    #pragma unroll
    for (int ci = 0; ci < 2; ++ci) {
      acc += w5s[ci * 3 + 0] * l4[ci][j - 1];
      acc += w5s[ci * 3 + 1] * l4[ci][j];
      acc += w5s[ci * 3 + 2] * l4[ci][j + 1];
    }
    y5[t0 + o] = (acc >= 0.f) ? acc : NEG * acc;
  }
}

// ---------------------------------------------------------------------------
// K3: logits = Wl @ y5 + bl. grid 1024 (8 rows/block), block 256.
// ---------------------------------------------------------------------------
__global__ __launch_bounds__(256) void k_matvec(
    const float* __restrict__ Wl, const float* __restrict__ bl,
    const float* __restrict__ y5, float* __restrict__ logits) {
  const int tid = threadIdx.x;
  const int r0 = blockIdx.x * 8;
  const float4* W4 = (const float4*)Wl;
  const float4* y4 = (const float4*)y5;

  float a[8];
  #pragma unroll
  for (int r = 0; r < 8; ++r) a[r] = 0.f;

  #pragma unroll 2
  for (int u = 0; u < 8; ++u) {
    int i = u * 256 + tid;
    float4 yv = y4[i];
    #pragma unroll
    for (int r = 0; r < 8; ++r) {
      float4 wv = W4[(r0 + r) * 2048 + i];
      a[r] += wv.x * yv.x + wv.y * yv.y + wv.z * yv.z + wv.w * yv.w;
    }
  }
  #pragma unroll
  for (int o = 32; o; o >>= 1) {
    #pragma unroll
    for (int r = 0; r < 8; ++r) a[r] += __shfl_down(a[r], o);
  }
  __shared__ float red[4][8];
  const int lane = tid & 63, wid = tid >> 6;
  if (lane == 0) {
    #pragma unroll
    for (int r = 0; r < 8; ++r) red[wid][r] = a[r];
  }
  __syncthreads();
  if (tid < 8) {
    float s = red[0][tid] + red[1][tid] + red[2][tid] + red[3][tid];
    logits[r0 + tid] = s + bl[r0 + tid];
  }
}

// ---------------------------------------------------------------------------
// K3.5: softmax stats over 8192 logits -> stats[0]=M, stats[1]=1/S. grid 1.
// ---------------------------------------------------------------------------
__global__ __launch_bounds__(256) void k_stats(
    const float* __restrict__ logits, float* __restrict__ stats) {
  __shared__ float red[4];
  const int tid = threadIdx.x;
  const int lane = tid & 63, wid = tid >> 6;

  float lv[32];
  #pragma unroll
  for (int i = 0; i < 32; ++i) lv[i] = logits[tid + 256 * i];

  float m = lv[0];
  #pragma unroll
  for (int i = 1; i < 32; ++i) m = fmaxf(m, lv[i]);
  #pragma unroll
  for (int o = 32; o; o >>= 1) m = fmaxf(m, __shfl_down(m, o));
  if (lane == 0) red[wid] = m;
  __syncthreads();
  const float M = fmaxf(fmaxf(red[0], red[1]), fmaxf(red[2], red[3]));
  __syncthreads();

  float s = 0.f;
  #pragma unroll
  for (int i = 0; i < 32; ++i) s += __expf(lv[i] - M);
  #pragma unroll
  for (int o = 32; o; o >>= 1) s += __shfl_down(s, o);
  if (lane == 0) red[wid] = s;
  __syncthreads();
  if (tid == 0) {
    float S = red[0] + red[1] + red[2] + red[3];
    stats[0] = M;
    stats[1] = 1.0f / S;
  }
}

// ---------------------------------------------------------------------------
// K4: weighted-sum partials. grid 1024 = 128 tc x 8 strips, block 256.
// wave wv handles 16 t; intra-block LDS reduce -> partial[128][2048].
// ---------------------------------------------------------------------------
__global__ __launch_bounds__(256) void k_wsum(
    const float* __restrict__ x, const float* __restrict__ logits,
    const float* __restrict__ stats, float* __restrict__ partial) {
  const int tid = threadIdx.x;
  const int lane = tid & 63, wv = tid >> 6;
  const int tc = blockIdx.x >> 3, strip = blockIdx.x & 7;
  const float M = stats[0], invS = stats[1];
  const float4* x4 = (const float4*)x;
  const int col = strip * 64 + lane;      // f4 column 0..511
  const int t0 = tc * 64 + wv * 16;

  float4 acc = make_float4(0.f, 0.f, 0.f, 0.f);
  #pragma unroll 4
  for (int tt = 0; tt < 16; ++tt) {
    int t = t0 + tt;
    float a = __expf(logits[t] - M) * invS;
    float4 xv = x4[t * 512 + col];
    acc.x += a * xv.x; acc.y += a * xv.y; acc.z += a * xv.z; acc.w += a * xv.w;
  }

  __shared__ float4 redx[4][64];
  redx[wv][lane] = acc;
  __syncthreads();
  if (wv == 0) {
    float4 s = redx[0][lane];
    #pragma unroll
    for (int w = 1; w < 4; ++w) {
      float4 v = redx[w][lane];
      s.x += v.x; s.y += v.y; s.z += v.z; s.w += v.w;
    }
    ((float4*)partial)[tc * 512 + col] = s;
  }
}

// ---------------------------------------------------------------------------
// K5: out[d] = sum_{tc<128} partial[tc][d]. grid 8, block 256.
// ---------------------------------------------------------------------------
__global__ __launch_bounds__(256) void k_reduce(
    const float* __restrict__ partial, float* __restrict__ out) {
  const int col = blockIdx.x * 256 + threadIdx.x;  // 0..2047
  float s = 0.f;
  #pragma unroll 8
  for (int tc = 0; tc < 128; ++tc) s += partial[tc * 2048 + col];
  out[col] = s;
}

// ---------------------------------------------------------------------------
extern "C" void kernel_launch(void* const* d_in, const int* in_sizes, int n_in,
                              void* d_out, int out_size, void* d_ws, size_t ws_size,
                              hipStream_t stream) {
  const float* x  = (const float*)d_in[0];
  const float* w1 = (const float*)d_in[1];
  const float* b1 = (const float*)d_in[2];
  const float* w2 = (const float*)d_in[3];
  const float* b2 = (const float*)d_in[4];
  const float* w3 = (const float*)d_in[5];
  const float* b3 = (const float*)d_in[6];
  const float* w4 = (const float*)d_in[7];
  const float* b4 = (const float*)d_in[8];
  const float* w5 = (const float*)d_in[9];
  const float* b5 = (const float*)d_in[10];
  const float* Wl = (const float*)d_in[11];
  const float* bl = (const float*)d_in[12];
  float* out = (float*)d_out;

  float* ws      = (float*)d_ws;
  float* out1p   = ws;                        // 16*16*8192 = 2097152
  float* y5      = out1p + 16 * 16 * SEQ;     // 8192
  float* logits  = y5 + SEQ;                  // 8192
  float* stats   = logits + SEQ;              // 16
  float* partial = stats + 16;                // 128*2048

  k_conv1 <<<512, 256, 0, stream>>>(x, w1, out1p);
  k_chain <<<128, 128, 0, stream>>>(out1p, b1, w2, b2, w3, b3, w4, b4, w5, b5, y5);
  k_matvec<<<1024, 256, 0, stream>>>(Wl, bl, y5, logits);
  k_stats <<<1, 256, 0, stream>>>(logits, stats);
  k_wsum  <<<1024, 256, 0, stream>>>(x, logits, stats, partial);
  k_reduce<<<8, 256, 0, stream>>>(partial, out);
}